// Round 3
// baseline (162.309 us; speedup 1.0000x reference)
//
#include <hip/hip_runtime.h>
#include <hip/hip_bf16.h>
#include <stdint.h>

// MoE dilated conv FFN: E=8, DM=512, DH=1024, K=3, DIL=2, PAD=2, N=128, L=128.
// bf16 MFMA 16x16x32 GEMMs; K-order kk = k*512 + c (tap-major chunks of 32 ch).
// B (activations) staged per c-chunk as LDS rows l'=l+2 with 2 zero pad rows each
// side; tap k reads row l+2k -> dilation/padding is a pure LDS row offset; ONE
// B tile serves all 3 taps. 2-sample blocks (expert counts all even).
// This round: 8-phase-style schedule (T3+T4+T5): per chunk, fine phases of
// {ds_read || staged global_load_lds -> counted vmcnt -> barrier -> lgkmcnt(0)
//  -> setprio(1) 16 MFMA setprio(0) -> barrier}; vmcnt never 0 in main loop.
// All staged tiles [row][32ch] (64B rows), XOR-swizzled (slot ^= (row>>1)&3),
// PRE-SWIZZLED in workspace so linear global_load_lds yields swizzled layout.

typedef __attribute__((ext_vector_type(8))) short short8;   // 8 bf16 = 4 VGPR
typedef __attribute__((ext_vector_type(4))) float f32x4;

#define DMV 512
#define DHV 1024

// workspace layout (bytes)
#define OFF_X   0ull                 // x_prep  [128][16][128][4][8] bf16 = 16 MB
#define OFF_H   (16ull << 20)        // h_prep  [128][32][128][4][8] bf16 = 32 MB
#define OFF_W1  (48ull << 20)        // w1_prep [8][16][8][3][128][4][8] bf16 = 24 MB
#define OFF_W2  (72ull << 20)        // w2_prep [8][32][4][3][128][4][8] bf16 = 24 MB

#define VMW(n) asm volatile("s_waitcnt vmcnt(" #n ")" ::: "memory")
#define VMNOP  do {} while (0)

__device__ __forceinline__ uint16_t f2bf(float f) {
  uint32_t u = __builtin_bit_cast(uint32_t, f);
  uint32_t r = (u + 0x7FFFu + ((u >> 16) & 1u)) >> 16;  // RTNE
  return (uint16_t)r;
}

__device__ __forceinline__ void async_copy16(const void* g, void* l) {
  __builtin_amdgcn_global_load_lds(
      (const __attribute__((address_space(1))) uint32_t*)g,
      (__attribute__((address_space(3))) uint32_t*)l, 16, 0, 0);
}

__device__ __forceinline__ float gelu_f(float x) {
  float u = 0.7978845608028654f * (x + 0.044715f * x * x * x);
  float t = __expf(2.0f * u);
  float th = 1.0f - 2.0f / (t + 1.0f);
  return 0.5f * x * (1.0f + th);
}

// inp [128][512][128] f32 -> x_prep chunk(s,cc,l,sub) holds
// c = cc*32 + ((sub ^ f(l+2))&3)*8 + j, value inp[s][c][l].  f(r)=(r>>1)&3.
__device__ __forceinline__ void prep_x_body(uint32_t t, const float* __restrict__ inp,
                                            uint16_t* __restrict__ xp) {
  uint32_t sub = t & 3u;
  uint32_t l = (t >> 2) & 127u;
  uint32_t cc = (t >> 9) & 15u;
  uint32_t s = t >> 13;
  uint32_t fl = ((l + 2u) >> 1) & 3u;
  uint32_t c0 = cc * 32u + ((sub ^ fl) & 3u) * 8u;
  const float* src = inp + ((size_t)s * DMV + c0) * 128u + l;
  uint32_t pk[4];
#pragma unroll
  for (int p = 0; p < 4; ++p) {
    uint32_t lo = f2bf(src[(size_t)(2 * p) * 128u]);
    uint32_t hi = f2bf(src[(size_t)(2 * p + 1) * 128u]);
    pk[p] = lo | (hi << 16);
  }
  uint4 v; v.x = pk[0]; v.y = pk[1]; v.z = pk[2]; v.w = pk[3];
  ((uint4*)xp)[t] = v;
}

// w [E][O][C][3] f32 -> wp [e][cc][mt][k][row][sub][8] bf16, swizzled.
__device__ __forceinline__ void prep_w_body(uint32_t t, const float* __restrict__ w,
                                            uint16_t* __restrict__ wp,
                                            int C, int mtBits, int ccBits) {
  uint32_t sub = t & 3u;
  uint32_t row = (t >> 2) & 127u;
  uint32_t t2 = t >> 9;
  uint32_t k = t2 % 3u;
  uint32_t t3 = t2 / 3u;
  uint32_t mt = t3 & ((1u << mtBits) - 1u);
  uint32_t t4 = t3 >> mtBits;
  uint32_t cc = t4 & ((1u << ccBits) - 1u);
  uint32_t e = t4 >> ccBits;
  uint32_t O = 128u << mtBits;
  uint32_t o = mt * 128u + row;
  uint32_t c0 = cc * 32u + ((sub ^ (row >> 1)) & 3u) * 8u;
  const float* src = w + (((size_t)e * O + o) * (uint32_t)C + c0) * 3u + k;
  uint32_t pk[4];
#pragma unroll
  for (int p = 0; p < 4; ++p) {
    uint32_t lo = f2bf(src[(size_t)(2 * p) * 3u]);
    uint32_t hi = f2bf(src[(size_t)(2 * p + 1) * 3u]);
    pk[p] = lo | (hi << 16);
  }
  uint4 v; v.x = pk[0]; v.y = pk[1]; v.z = pk[2]; v.w = pk[3];
  ((uint4*)wp)[t] = v;
}

__global__ void prep_all(const float* __restrict__ inp,
                         const float* __restrict__ w1, const float* __restrict__ w2,
                         uint16_t* __restrict__ xp,
                         uint16_t* __restrict__ w1p, uint16_t* __restrict__ w2p) {
  uint32_t b = blockIdx.x, tid = threadIdx.x;
  if (b < 4096u)        prep_x_body(b * 256u + tid, inp, xp);
  else if (b < 10240u)  prep_w_body((b - 4096u) * 256u + tid, w1, w1p, 512, 3, 4);
  else                  prep_w_body((b - 10240u) * 256u + tid, w2, w2p, 1024, 2, 5);
}

// one fine phase: ds_read fragments (current buffer) || issue staging loads,
// counted vmcnt, barrier, lgkm drain, prioritized 16-MFMA cluster, barrier.
#define PHASE_STEP(K, HH, READB, STAGE_BODY, VM_BODY)                          \
  {                                                                            \
    short8 af_[4];                                                             \
    _Pragma("unroll") for (int q = 0; q < 4; ++q)                              \
      af_[q] = *(const short8*)(br + aOff[(HH) * 4 + q] + (uint32_t)(K) * 8192u); \
    if (READB) {                                                               \
      _Pragma("unroll") for (int bq = 0; bq < 4; ++bq) {                       \
        uint32_t r_ = lB[bq] + 2u * (uint32_t)(K);                             \
        bfk[bq] = *(const short8*)(br + pOff + r_ * 64u +                      \
                    (((uint32_t)kg ^ (r_ >> 1)) & 3u) * 16u);                  \
      }                                                                        \
    }                                                                          \
    STAGE_BODY;                                                                \
    VM_BODY;                                                                   \
    __builtin_amdgcn_s_barrier();                                              \
    asm volatile("s_waitcnt lgkmcnt(0)" ::: "memory");                         \
    __builtin_amdgcn_s_setprio(1);                                             \
    _Pragma("unroll") for (int q = 0; q < 4; ++q)                              \
      _Pragma("unroll") for (int bq = 0; bq < 4; ++bq)                         \
        acc[(HH) * 4 + q][bq] = __builtin_amdgcn_mfma_f32_16x16x32_bf16(       \
            af_[q], bfk[bq], acc[(HH) * 4 + q][bq], 0, 0, 0);                  \
    __builtin_amdgcn_s_setprio(0);                                             \
    __builtin_amdgcn_s_barrier();                                              \
  }

// PHASE 1: 256x256 tile (M=256 of DH, N=2 samples x 128), CC=16 chunks, 6 phases.
// PHASE 2: 128x256 tile (M=128 of DM),                   CC=32 chunks, 3 phases.
template <int PHASE>
__global__ __launch_bounds__(512, 2) void conv_mfma(
    const uint16_t* __restrict__ bprep, const uint16_t* __restrict__ wprep,
    const float* __restrict__ bias, const int* __restrict__ cnt,
    uint16_t* __restrict__ hout, float* __restrict__ fout) {
  constexpr int CC = (PHASE == 1) ? 16 : 32;        // Cin/32
  constexpr int HALVES = (PHASE == 1) ? 2 : 1;      // 128-row prep tiles per block
  constexpr int MTP = (PHASE == 1) ? 8 : 4;         // prep mt tile count
  constexpr int AREP = 4 * HALVES;
  constexpr int OO = (PHASE == 1) ? DHV : DMV;
  constexpr uint32_t AS = HALVES * 24576u;          // A bytes per buffer
  constexpr uint32_t BUFS = AS + 16896u;            // + B: 2 samples x 132 x 64B

  // chunked XCD swizzle (256 = 8 XCD x 32, bijective)
  uint32_t b = blockIdx.x;
  uint32_t work = (b & 7u) * 32u + (b >> 3);
  const int pr = work & 63;          // sample pair: samples 2pr, 2pr+1
  const int mt = work >> 6;
  int e = 0;
  {
    int cum = cnt[0];
    while (2 * pr >= cum && e < 7) { ++e; cum += cnt[e]; }
  }
  const int tid = threadIdx.x;
  const int lane = tid & 63;
  const int wv = tid >> 6;
  const int wr = wv >> 2, wc = wv & 3;
  const int l15 = lane & 15, kg = lane >> 4;

  __shared__ __align__(16) uint8_t lds[2 * BUFS];

  // invariant LDS read offsets (A tile of this wave: h = wr for conv1)
  uint32_t aOff[AREP];
#pragma unroll
  for (int a = 0; a < AREP; ++a) {
    uint32_t ri = (HALVES == 2) ? (uint32_t)(a * 16 + l15)
                                : (uint32_t)(wr * 64 + a * 16 + l15);
    uint32_t base = (HALVES == 2) ? (uint32_t)wr * 24576u : 0u;
    aOff[a] = base + ri * 64u + (((uint32_t)kg ^ (ri >> 1)) & 3u) * 16u;
  }
  uint32_t lB[4];
#pragma unroll
  for (int bq = 0; bq < 4; ++bq) lB[bq] = (uint32_t)((wc & 1) * 64 + bq * 16 + l15);
  const uint32_t pOff = AS + (uint32_t)(wc >> 1) * 8448u;
  const int mtBase = (PHASE == 1) ? mt * 2 : mt;

  const uint16_t* wTile0 = wprep + ((size_t)e * CC * MTP + mtBase) * 12288;
  auto SA = [&](uint8_t* bw, int ccn, int h, int k) {  // one 8KB A tile (1 instr/wave)
    async_copy16(wTile0 + (size_t)ccn * (MTP * 12288) + (h * 3 + k) * 4096 + tid * 8,
                 bw + (uint32_t)(h * 3 + k) * 8192u + (uint32_t)tid * 16);
  };
  auto SBL = [&](uint8_t* bw, int ccn, int p) {        // one sample's B rows 2..129
    async_copy16(bprep + ((size_t)(2 * pr + p) * CC + ccn) * 4096 + tid * 8,
                 bw + AS + (uint32_t)p * 8448u + 128u + (uint32_t)tid * 16);
  };

  // zero pad rows l' = 0,1,130,131 (both buffers, both samples) — persist
  if (tid < 64) {
    uint32_t n = (uint32_t)tid >> 5, rest = (uint32_t)tid & 31u;
    uint32_t p = rest >> 4, ri = (rest >> 2) & 3u, sb = rest & 3u;
    uint32_t rowByte = (ri < 2) ? ri * 64u : (8320u + (ri - 2) * 64u);
    uint4 z = make_uint4(0, 0, 0, 0);
    *(uint4*)(lds + n * BUFS + AS + p * 8448u + rowByte + sb * 16u) = z;
  }
  asm volatile("s_waitcnt lgkmcnt(0)" ::: "memory");   // pad writes drained

  // prologue: issue chunk-0 loads in need-order (B first), partial wait, barrier
  if (PHASE == 1) {
    SBL(lds, 0, 0); SBL(lds, 0, 1);
    SA(lds, 0, 0, 0); SA(lds, 0, 1, 0);
    SA(lds, 0, 0, 1); SA(lds, 0, 1, 1);
    SA(lds, 0, 0, 2); SA(lds, 0, 1, 2);
    VMW(4);                                            // B,B,A00,A10 done
  } else {
    SBL(lds, 0, 0); SBL(lds, 0, 1);
    SA(lds, 0, 0, 0); SA(lds, 0, 0, 1); SA(lds, 0, 0, 2);
    VMW(2);                                            // B,B,A0 done
  }
  __builtin_amdgcn_s_barrier();

  f32x4 acc[AREP][4] = {};
  short8 bfk[4];

  if (PHASE == 1) {
#pragma unroll 1
    for (int cc = 0; cc < CC - 1; ++cc) {
      const uint8_t* br = lds + (uint32_t)(cc & 1) * BUFS;
      uint8_t* bw = lds + (uint32_t)((cc & 1) ^ 1) * BUFS;
      const int cn = cc + 1;
      PHASE_STEP(0, 0, true,  { SBL(bw, cn, 0); SBL(bw, cn, 1); }, VMNOP);
      PHASE_STEP(0, 1, false, { SA(bw, cn, 0, 0); SA(bw, cn, 1, 0); }, VMW(6));
      PHASE_STEP(1, 0, true,  { SA(bw, cn, 0, 1); }, VMNOP);
      PHASE_STEP(1, 1, false, { SA(bw, cn, 1, 1); }, VMW(6));
      PHASE_STEP(2, 0, true,  { SA(bw, cn, 0, 2); }, VMNOP);
      PHASE_STEP(2, 1, false, { SA(bw, cn, 1, 2); }, VMW(4));
    }
    {  // last chunk: no staging, drain tail
      const uint8_t* br = lds + (uint32_t)((CC - 1) & 1) * BUFS;
      PHASE_STEP(0, 0, true,  {}, VMNOP);
      PHASE_STEP(0, 1, false, {}, VMW(2));
      PHASE_STEP(1, 0, true,  {}, VMNOP);
      PHASE_STEP(1, 1, false, {}, VMW(0));
      PHASE_STEP(2, 0, true,  {}, VMNOP);
      PHASE_STEP(2, 1, false, {}, VMNOP);
    }
  } else {
#pragma unroll 1
    for (int cc = 0; cc < CC - 1; ++cc) {
      const uint8_t* br = lds + (uint32_t)(cc & 1) * BUFS;
      uint8_t* bw = lds + (uint32_t)((cc & 1) ^ 1) * BUFS;
      const int cn = cc + 1;
      PHASE_STEP(0, 0, true, { SBL(bw, cn, 0); SBL(bw, cn, 1); SA(bw, cn, 0, 0); }, VMW(4));
      PHASE_STEP(1, 0, true, { SA(bw, cn, 0, 1); }, VMW(4));
      PHASE_STEP(2, 0, true, { SA(bw, cn, 0, 2); }, VMW(2));
    }
    {
      const uint8_t* br = lds + (uint32_t)((CC - 1) & 1) * BUFS;
      PHASE_STEP(0, 0, true, {}, VMW(1));
      PHASE_STEP(1, 0, true, {}, VMW(0));
      PHASE_STEP(2, 0, true, {}, VMNOP);
    }
  }

  const int p = wc >> 1;
  const int s = 2 * pr + p;
  if (PHASE == 1) {
    // bias + gelu + bf16, write directly in h_prep's swizzled chunk layout
#pragma unroll
    for (int a = 0; a < AREP; ++a) {
      int ob = mt * 256 + wr * 128 + a * 16 + kg * 4;
      float4 bv = *(const float4*)(bias + (size_t)e * OO + ob);
      int cc2 = mt * 8 + wr * 4 + (a >> 1);
      uint32_t g = (uint32_t)((a & 1) * 2 + (kg >> 1));
      uint32_t j0 = (uint32_t)((kg & 1) * 4);
#pragma unroll
      for (int bq = 0; bq < 4; ++bq) {
        int l = (wc & 1) * 64 + bq * 16 + l15;
        uint32_t flq = ((uint32_t)(l + 2) >> 1) & 3u;
        uint32_t sub = g ^ flq;
        float v0 = gelu_f(acc[a][bq][0] + bv.x);
        float v1 = gelu_f(acc[a][bq][1] + bv.y);
        float v2 = gelu_f(acc[a][bq][2] + bv.z);
        float v3 = gelu_f(acc[a][bq][3] + bv.w);
        uint2 pk;
        pk.x = (uint32_t)f2bf(v0) | ((uint32_t)f2bf(v1) << 16);
        pk.y = (uint32_t)f2bf(v2) | ((uint32_t)f2bf(v3) << 16);
        size_t ci = ((size_t)s * 32 + cc2) * 128 + l;
        *(uint2*)(hout + ci * 32 + sub * 8 + j0) = pk;
      }
    }
  } else {
#pragma unroll
    for (int a = 0; a < AREP; ++a) {
      int ob = mt * 128 + wr * 64 + a * 16 + kg * 4;
      float4 bv = *(const float4*)(bias + (size_t)e * OO + ob);
      float bvr[4] = {bv.x, bv.y, bv.z, bv.w};
      float* op = fout + ((size_t)s * DMV + ob) * 128;
#pragma unroll
      for (int bq = 0; bq < 4; ++bq) {
        int l = (wc & 1) * 64 + bq * 16 + l15;
#pragma unroll
        for (int r = 0; r < 4; ++r)
          op[(size_t)r * 128 + l] = acc[a][bq][r] + bvr[r];
      }
    }
  }
}

extern "C" void kernel_launch(void* const* d_in, const int* in_sizes, int n_in,
                              void* d_out, int out_size, void* d_ws, size_t ws_size,
                              hipStream_t stream) {
  const float* inp = (const float*)d_in[0];
  const int* cnt = (const int*)d_in[1];
  const float* w1 = (const float*)d_in[2];
  const float* b1 = (const float*)d_in[3];
  const float* w2 = (const float*)d_in[4];
  const float* b2 = (const float*)d_in[5];
  float* out = (float*)d_out;
  uint8_t* ws = (uint8_t*)d_ws;
  uint16_t* xp = (uint16_t*)(ws + OFF_X);
  uint16_t* hp = (uint16_t*)(ws + OFF_H);
  uint16_t* w1p = (uint16_t*)(ws + OFF_W1);
  uint16_t* w2p = (uint16_t*)(ws + OFF_W2);

  prep_all<<<dim3(16384), dim3(256), 0, stream>>>(inp, w1, w2, xp, w1p, w2p);
  conv_mfma<1><<<dim3(256), dim3(512), 0, stream>>>(xp, w1p, b1, cnt, hp, nullptr);
  conv_mfma<2><<<dim3(256), dim3(512), 0, stream>>>(hp, w2p, b2, cnt, nullptr, out);
}

// Round 4
// 140.833 us; speedup vs baseline: 1.1525x; 1.1525x over previous
//
#include <hip/hip_runtime.h>
#include <hip/hip_bf16.h>
#include <stdint.h>

// MoE dilated conv FFN: E=8, DM=512, DH=1024, K=3, DIL=2, PAD=2, N=128, L=128.
// bf16 MFMA 16x16x32 GEMMs; K-order kk = k*512 + c (tap-major chunks of 32 ch).
// B (activations) staged per c-chunk as LDS rows l'=l+2 with 2 zero pad rows each
// side; tap k reads row l+2k -> dilation/padding is a pure LDS row offset; ONE
// B tile serves all 3 taps. 2-sample blocks (expert counts all even).
// Conv schedule: fine phases (T3+T4+T5): {ds_read || staged global_load_lds ->
// counted vmcnt -> barrier -> lgkmcnt(0) -> setprio(1) 16 MFMA setprio(0) ->
// barrier}; vmcnt never 0 in main loop. Tiles [row][32ch] (64B rows),
// XOR-swizzled (slot ^= (row>>1)&3), PRE-SWIZZLED in workspace.
// This round: coalesced preps (R3's fused prep was 80us at 2.9 TB/s from
// scalar strided loads): prep_w reads 48B contiguous/thread (4ch x 3taps),
// prep_x does a block LDS transpose with float4 reads along L.

typedef __attribute__((ext_vector_type(8))) short short8;   // 8 bf16 = 4 VGPR
typedef __attribute__((ext_vector_type(4))) float f32x4;

#define DMV 512
#define DHV 1024

// workspace layout (bytes)
#define OFF_X   0ull                 // x_prep  [128][16][128][4][8] bf16 = 16 MB
#define OFF_H   (16ull << 20)        // h_prep  [128][32][128][4][8] bf16 = 32 MB
#define OFF_W1  (48ull << 20)        // w1_prep [8][16][8][3][128][4][8] bf16 = 24 MB
#define OFF_W2  (72ull << 20)        // w2_prep [8][32][4][3][128][4][8] bf16 = 24 MB

#define VMW(n) asm volatile("s_waitcnt vmcnt(" #n ")" ::: "memory")
#define VMNOP  do {} while (0)

__device__ __forceinline__ uint16_t f2bf(float f) {
  uint32_t u = __builtin_bit_cast(uint32_t, f);
  uint32_t r = (u + 0x7FFFu + ((u >> 16) & 1u)) >> 16;  // RTNE
  return (uint16_t)r;
}

__device__ __forceinline__ void async_copy16(const void* g, void* l) {
  __builtin_amdgcn_global_load_lds(
      (const __attribute__((address_space(1))) uint32_t*)g,
      (__attribute__((address_space(3))) uint32_t*)l, 16, 0, 0);
}

__device__ __forceinline__ float gelu_f(float x) {
  float u = 0.7978845608028654f * (x + 0.044715f * x * x * x);
  float t = __expf(2.0f * u);
  float th = 1.0f - 2.0f / (t + 1.0f);
  return 0.5f * x * (1.0f + th);
}

// ---- prep_x: block = (s, cc) handles a [32ch][128L] f32 tile via LDS transpose.
// out chunk(s,cc,l,sub) holds c = cc*32 + ((sub^fl)&3)*8 + j, fl = ((l+2)>>1)&3.
__global__ __launch_bounds__(256) void prep_x_t(const float* __restrict__ inp,
                                                uint16_t* __restrict__ xp) {
  uint32_t b = blockIdx.x;              // 2048 = 128 s x 16 cc
  uint32_t s = b >> 4, cc = b & 15u;
  __shared__ uint16_t xs[32][132];      // row stride 264B
  uint32_t t = threadIdx.x;
  const float* src0 = inp + ((size_t)s * DMV + cc * 32u) * 128u;
#pragma unroll
  for (int i = 0; i < 4; ++i) {
    uint32_t idx = (uint32_t)i * 256u + t;     // [0,1024): 32ch x 32 l-quads
    uint32_t ch = idx >> 5, l4 = idx & 31u;
    float4 f = *(const float4*)(src0 + ch * 128u + l4 * 4u);
    uint2 pk;
    pk.x = (uint32_t)f2bf(f.x) | ((uint32_t)f2bf(f.y) << 16);
    pk.y = (uint32_t)f2bf(f.z) | ((uint32_t)f2bf(f.w) << 16);
    *(uint2*)&xs[ch][l4 * 4u] = pk;
  }
  __syncthreads();
  uint32_t l = t >> 1, half = t & 1u;
  uint32_t fl = ((l + 2u) >> 1) & 3u;
#pragma unroll
  for (int hi = 0; hi < 2; ++hi) {
    uint32_t sub = half * 2u + (uint32_t)hi;
    uint32_t cg = (sub ^ fl) & 3u;
    uint32_t pk[4];
#pragma unroll
    for (int p2 = 0; p2 < 4; ++p2) {
      uint32_t c0 = cg * 8u + (uint32_t)p2 * 2u;
      pk[p2] = (uint32_t)xs[c0][l] | ((uint32_t)xs[c0 + 1][l] << 16);
    }
    uint4 v; v.x = pk[0]; v.y = pk[1]; v.z = pk[2]; v.w = pk[3];
    size_t slot = (((size_t)s * 16u + cc) * 128u + l) * 4u + sub;
    *(uint4*)(xp + slot * 8u) = v;             // consecutive t -> contiguous 64B
  }
}

// ---- prep_w: thread = (e, o, cg) reads 12 contiguous floats (4ch x 3 taps),
// writes 3x uint2 into wp [e][cc][mt][k][row][sub][8] (swizzled sub).
template <int LOGCG, int LOGO>
__global__ __launch_bounds__(256) void prep_w_c(const float* __restrict__ w,
                                                uint16_t* __restrict__ wp) {
  constexpr uint32_t C = 4u << LOGCG;
  constexpr uint32_t CCn = C >> 5;
  constexpr uint32_t MTn = 1u << (LOGO - 7);
  uint32_t t = blockIdx.x * 256u + threadIdx.x;
  uint32_t cg = t & ((1u << LOGCG) - 1u);
  uint32_t o = (t >> LOGCG) & ((1u << LOGO) - 1u);
  uint32_t e = t >> (LOGCG + LOGO);
  uint32_t row = o & 127u, mt = o >> 7;
  const float* src = w + (((size_t)(e << LOGO) + o) * C + cg * 4u) * 3u;
  float4 f0 = *(const float4*)(src);           // c0k0 c0k1 c0k2 c1k0
  float4 f1 = *(const float4*)(src + 4);       // c1k1 c1k2 c2k0 c2k1
  float4 f2 = *(const float4*)(src + 8);       // c2k2 c3k0 c3k1 c3k2
  uint32_t cc = cg >> 3;
  uint32_t sub = ((cg >> 1) & 3u) ^ ((row >> 1) & 3u);
  uint32_t j0 = (cg & 1u) * 4u;
  size_t base = (((size_t)e * CCn + cc) * MTn + mt) * 3u;
  uint2 q;
  // k = 0
  q.x = (uint32_t)f2bf(f0.x) | ((uint32_t)f2bf(f0.w) << 16);
  q.y = (uint32_t)f2bf(f1.z) | ((uint32_t)f2bf(f2.y) << 16);
  *(uint2*)(wp + ((base + 0u) * 128u + row) * 32u + sub * 8u + j0) = q;
  // k = 1
  q.x = (uint32_t)f2bf(f0.y) | ((uint32_t)f2bf(f1.x) << 16);
  q.y = (uint32_t)f2bf(f1.w) | ((uint32_t)f2bf(f2.z) << 16);
  *(uint2*)(wp + ((base + 1u) * 128u + row) * 32u + sub * 8u + j0) = q;
  // k = 2
  q.x = (uint32_t)f2bf(f0.z) | ((uint32_t)f2bf(f1.y) << 16);
  q.y = (uint32_t)f2bf(f2.x) | ((uint32_t)f2bf(f2.w) << 16);
  *(uint2*)(wp + ((base + 2u) * 128u + row) * 32u + sub * 8u + j0) = q;
}

// one fine phase: ds_read fragments (current buffer) || issue staging loads,
// counted vmcnt, barrier, lgkm drain, prioritized 16-MFMA cluster, barrier.
#define PHASE_STEP(K, HH, READB, STAGE_BODY, VM_BODY)                          \
  {                                                                            \
    short8 af_[4];                                                             \
    _Pragma("unroll") for (int q = 0; q < 4; ++q)                              \
      af_[q] = *(const short8*)(br + aOff[(HH) * 4 + q] + (uint32_t)(K) * 8192u); \
    if (READB) {                                                               \
      _Pragma("unroll") for (int bq = 0; bq < 4; ++bq) {                       \
        uint32_t r_ = lB[bq] + 2u * (uint32_t)(K);                             \
        bfk[bq] = *(const short8*)(br + pOff + r_ * 64u +                      \
                    (((uint32_t)kg ^ (r_ >> 1)) & 3u) * 16u);                  \
      }                                                                        \
    }                                                                          \
    STAGE_BODY;                                                                \
    VM_BODY;                                                                   \
    __builtin_amdgcn_s_barrier();                                              \
    asm volatile("s_waitcnt lgkmcnt(0)" ::: "memory");                         \
    __builtin_amdgcn_s_setprio(1);                                             \
    _Pragma("unroll") for (int q = 0; q < 4; ++q)                              \
      _Pragma("unroll") for (int bq = 0; bq < 4; ++bq)                         \
        acc[(HH) * 4 + q][bq] = __builtin_amdgcn_mfma_f32_16x16x32_bf16(       \
            af_[q], bfk[bq], acc[(HH) * 4 + q][bq], 0, 0, 0);                  \
    __builtin_amdgcn_s_setprio(0);                                             \
    __builtin_amdgcn_s_barrier();                                              \
  }

// PHASE 1: 256x256 tile (M=256 of DH, N=2 samples x 128), CC=16 chunks, 6 phases.
// PHASE 2: 128x256 tile (M=128 of DM),                   CC=32 chunks, 3 phases.
template <int PHASE>
__global__ __launch_bounds__(512, 2) void conv_mfma(
    const uint16_t* __restrict__ bprep, const uint16_t* __restrict__ wprep,
    const float* __restrict__ bias, const int* __restrict__ cnt,
    uint16_t* __restrict__ hout, float* __restrict__ fout) {
  constexpr int CC = (PHASE == 1) ? 16 : 32;        // Cin/32
  constexpr int HALVES = (PHASE == 1) ? 2 : 1;      // 128-row prep tiles per block
  constexpr int MTP = (PHASE == 1) ? 8 : 4;         // prep mt tile count
  constexpr int AREP = 4 * HALVES;
  constexpr int OO = (PHASE == 1) ? DHV : DMV;
  constexpr uint32_t AS = HALVES * 24576u;          // A bytes per buffer
  constexpr uint32_t BUFS = AS + 16896u;            // + B: 2 samples x 132 x 64B

  // chunked XCD swizzle (256 = 8 XCD x 32, bijective)
  uint32_t b = blockIdx.x;
  uint32_t work = (b & 7u) * 32u + (b >> 3);
  const int pr = work & 63;          // sample pair: samples 2pr, 2pr+1
  const int mt = work >> 6;
  int e = 0;
  {
    int cum = cnt[0];
    while (2 * pr >= cum && e < 7) { ++e; cum += cnt[e]; }
  }
  const int tid = threadIdx.x;
  const int lane = tid & 63;
  const int wv = tid >> 6;
  const int wr = wv >> 2, wc = wv & 3;
  const int l15 = lane & 15, kg = lane >> 4;

  __shared__ __align__(16) uint8_t lds[2 * BUFS];

  // invariant LDS read offsets (A tile of this wave: h = wr for conv1)
  uint32_t aOff[AREP];
#pragma unroll
  for (int a = 0; a < AREP; ++a) {
    uint32_t ri = (HALVES == 2) ? (uint32_t)(a * 16 + l15)
                                : (uint32_t)(wr * 64 + a * 16 + l15);
    uint32_t base = (HALVES == 2) ? (uint32_t)wr * 24576u : 0u;
    aOff[a] = base + ri * 64u + (((uint32_t)kg ^ (ri >> 1)) & 3u) * 16u;
  }
  uint32_t lB[4];
#pragma unroll
  for (int bq = 0; bq < 4; ++bq) lB[bq] = (uint32_t)((wc & 1) * 64 + bq * 16 + l15);
  const uint32_t pOff = AS + (uint32_t)(wc >> 1) * 8448u;
  const int mtBase = (PHASE == 1) ? mt * 2 : mt;

  const uint16_t* wTile0 = wprep + ((size_t)e * CC * MTP + mtBase) * 12288;
  auto SA = [&](uint8_t* bw, int ccn, int h, int k) {  // one 8KB A tile (1 instr/wave)
    async_copy16(wTile0 + (size_t)ccn * (MTP * 12288) + (h * 3 + k) * 4096 + tid * 8,
                 bw + (uint32_t)(h * 3 + k) * 8192u + (uint32_t)tid * 16);
  };
  auto SBL = [&](uint8_t* bw, int ccn, int p) {        // one sample's B rows 2..129
    async_copy16(bprep + ((size_t)(2 * pr + p) * CC + ccn) * 4096 + tid * 8,
                 bw + AS + (uint32_t)p * 8448u + 128u + (uint32_t)tid * 16);
  };

  // zero pad rows l' = 0,1,130,131 (both buffers, both samples) — persist
  if (tid < 64) {
    uint32_t n = (uint32_t)tid >> 5, rest = (uint32_t)tid & 31u;
    uint32_t p = rest >> 4, ri = (rest >> 2) & 3u, sb = rest & 3u;
    uint32_t rowByte = (ri < 2) ? ri * 64u : (8320u + (ri - 2) * 64u);
    uint4 z = make_uint4(0, 0, 0, 0);
    *(uint4*)(lds + n * BUFS + AS + p * 8448u + rowByte + sb * 16u) = z;
  }
  asm volatile("s_waitcnt lgkmcnt(0)" ::: "memory");   // pad writes drained

  // prologue: issue chunk-0 loads in need-order (B first), partial wait, barrier
  if (PHASE == 1) {
    SBL(lds, 0, 0); SBL(lds, 0, 1);
    SA(lds, 0, 0, 0); SA(lds, 0, 1, 0);
    SA(lds, 0, 0, 1); SA(lds, 0, 1, 1);
    SA(lds, 0, 0, 2); SA(lds, 0, 1, 2);
    VMW(4);                                            // B,B,A00,A10 done
  } else {
    SBL(lds, 0, 0); SBL(lds, 0, 1);
    SA(lds, 0, 0, 0); SA(lds, 0, 0, 1); SA(lds, 0, 0, 2);
    VMW(2);                                            // B,B,A0 done
  }
  __builtin_amdgcn_s_barrier();

  f32x4 acc[AREP][4] = {};
  short8 bfk[4];

  if (PHASE == 1) {
#pragma unroll 1
    for (int cc = 0; cc < CC - 1; ++cc) {
      const uint8_t* br = lds + (uint32_t)(cc & 1) * BUFS;
      uint8_t* bw = lds + (uint32_t)((cc & 1) ^ 1) * BUFS;
      const int cn = cc + 1;
      PHASE_STEP(0, 0, true,  { SBL(bw, cn, 0); SBL(bw, cn, 1); }, VMNOP);
      PHASE_STEP(0, 1, false, { SA(bw, cn, 0, 0); SA(bw, cn, 1, 0); }, VMW(6));
      PHASE_STEP(1, 0, true,  { SA(bw, cn, 0, 1); }, VMNOP);
      PHASE_STEP(1, 1, false, { SA(bw, cn, 1, 1); }, VMW(6));
      PHASE_STEP(2, 0, true,  { SA(bw, cn, 0, 2); }, VMNOP);
      PHASE_STEP(2, 1, false, { SA(bw, cn, 1, 2); }, VMW(4));
    }
    {  // last chunk: no staging, drain tail
      const uint8_t* br = lds + (uint32_t)((CC - 1) & 1) * BUFS;
      PHASE_STEP(0, 0, true,  {}, VMNOP);
      PHASE_STEP(0, 1, false, {}, VMW(2));
      PHASE_STEP(1, 0, true,  {}, VMNOP);
      PHASE_STEP(1, 1, false, {}, VMW(0));
      PHASE_STEP(2, 0, true,  {}, VMNOP);
      PHASE_STEP(2, 1, false, {}, VMNOP);
    }
  } else {
#pragma unroll 1
    for (int cc = 0; cc < CC - 1; ++cc) {
      const uint8_t* br = lds + (uint32_t)(cc & 1) * BUFS;
      uint8_t* bw = lds + (uint32_t)((cc & 1) ^ 1) * BUFS;
      const int cn = cc + 1;
      PHASE_STEP(0, 0, true, { SBL(bw, cn, 0); SBL(bw, cn, 1); SA(bw, cn, 0, 0); }, VMW(4));
      PHASE_STEP(1, 0, true, { SA(bw, cn, 0, 1); }, VMW(4));
      PHASE_STEP(2, 0, true, { SA(bw, cn, 0, 2); }, VMW(2));
    }
    {
      const uint8_t* br = lds + (uint32_t)((CC - 1) & 1) * BUFS;
      PHASE_STEP(0, 0, true, {}, VMW(1));
      PHASE_STEP(1, 0, true, {}, VMW(0));
      PHASE_STEP(2, 0, true, {}, VMNOP);
    }
  }

  const int p = wc >> 1;
  const int s = 2 * pr + p;
  if (PHASE == 1) {
    // bias + gelu + bf16, write directly in h_prep's swizzled chunk layout
#pragma unroll
    for (int a = 0; a < AREP; ++a) {
      int ob = mt * 256 + wr * 128 + a * 16 + kg * 4;
      float4 bv = *(const float4*)(bias + (size_t)e * OO + ob);
      int cc2 = mt * 8 + wr * 4 + (a >> 1);
      uint32_t g = (uint32_t)((a & 1) * 2 + (kg >> 1));
      uint32_t j0 = (uint32_t)((kg & 1) * 4);
#pragma unroll
      for (int bq = 0; bq < 4; ++bq) {
        int l = (wc & 1) * 64 + bq * 16 + l15;
        uint32_t flq = ((uint32_t)(l + 2) >> 1) & 3u;
        uint32_t sub = g ^ flq;
        float v0 = gelu_f(acc[a][bq][0] + bv.x);
        float v1 = gelu_f(acc[a][bq][1] + bv.y);
        float v2 = gelu_f(acc[a][bq][2] + bv.z);
        float v3 = gelu_f(acc[a][bq][3] + bv.w);
        uint2 pk;
        pk.x = (uint32_t)f2bf(v0) | ((uint32_t)f2bf(v1) << 16);
        pk.y = (uint32_t)f2bf(v2) | ((uint32_t)f2bf(v3) << 16);
        size_t ci = ((size_t)s * 32 + cc2) * 128 + l;
        *(uint2*)(hout + ci * 32 + sub * 8 + j0) = pk;
      }
    }
  } else {
#pragma unroll
    for (int a = 0; a < AREP; ++a) {
      int ob = mt * 128 + wr * 64 + a * 16 + kg * 4;
      float4 bv = *(const float4*)(bias + (size_t)e * OO + ob);
      float bvr[4] = {bv.x, bv.y, bv.z, bv.w};
      float* op = fout + ((size_t)s * DMV + ob) * 128;
#pragma unroll
      for (int bq = 0; bq < 4; ++bq) {
        int l = (wc & 1) * 64 + bq * 16 + l15;
#pragma unroll
        for (int r = 0; r < 4; ++r)
          op[(size_t)r * 128 + l] = acc[a][bq][r] + bvr[r];
      }
    }
  }
}

extern "C" void kernel_launch(void* const* d_in, const int* in_sizes, int n_in,
                              void* d_out, int out_size, void* d_ws, size_t ws_size,
                              hipStream_t stream) {
  const float* inp = (const float*)d_in[0];
  const int* cnt = (const int*)d_in[1];
  const float* w1 = (const float*)d_in[2];
  const float* b1 = (const float*)d_in[3];
  const float* w2 = (const float*)d_in[4];
  const float* b2 = (const float*)d_in[5];
  float* out = (float*)d_out;
  uint8_t* ws = (uint8_t*)d_ws;
  uint16_t* xp = (uint16_t*)(ws + OFF_X);
  uint16_t* hp = (uint16_t*)(ws + OFF_H);
  uint16_t* w1p = (uint16_t*)(ws + OFF_W1);
  uint16_t* w2p = (uint16_t*)(ws + OFF_W2);

  prep_x_t<<<dim3(2048), dim3(256), 0, stream>>>(inp, xp);
  prep_w_c<7, 10><<<dim3(4096), dim3(256), 0, stream>>>(w1, w1p);
  prep_w_c<8, 9><<<dim3(4096), dim3(256), 0, stream>>>(w2, w2p);
  conv_mfma<1><<<dim3(256), dim3(512), 0, stream>>>(xp, w1p, b1, cnt, hp, nullptr);
  conv_mfma<2><<<dim3(256), dim3(512), 0, stream>>>(hp, w2p, b2, cnt, nullptr, out);
}